// Round 11
// baseline (23.503 us; speedup 1.0000x reference)
//
#include <hip/hip_runtime.h>
#include <math.h>

#define N_A 64
#define N_B 128
#define N_C 128
#define D_IN 256
#define D_H 32
#define NHEADS 4
#define DMODEL (D_H * NHEADS)   // 128

// Workspace layout (float offsets)
#define OFF_Q    0
#define OFF_KB   (OFF_Q   + N_A*DMODEL)
#define OFF_KC   (OFF_KB  + N_B*DMODEL)
#define OFF_VB   (OFF_KC  + N_C*DMODEL)
#define OFF_VC   (OFF_VB  + N_B*DMODEL)
#define OFF_PB   (OFF_VC  + N_C*DMODEL)      // [b][h][kk]  2048
#define OFF_PC   (OFF_PB  + N_B*NHEADS*4)    // diag PCX [h][cc] 512

#define SCALE 0.17677669529663687f  // 1/sqrt(32)

__device__ __forceinline__ float dot4(float4 a, float4 b) {
  return fmaf(a.x, b.x, fmaf(a.y, b.y, fmaf(a.z, b.z, a.w * b.w)));
}

// K-tile swizzle ([128][32] floats): spreads row-groups across 16B slots.
__device__ __forceinline__ int kswz(int row, int d) {
  return (row * 32 + d) ^ (((row >> 3) & 7) << 2);
}

// Ebc swizzle ([128][128] floats): row-dependent window for conflict-free
// GEMM stores, U-pass reads and output reads.
__device__ __forceinline__ int ebx(int b, int c) {
  return b * 128 + (c ^ (((b ^ (b >> 3)) & 7) << 2));
}

// ============ K1: projections, 4 rows/block with W reuse + pb/pcx tail ======
// 144 blocks x 512 threads. ks = t>>7 (4-way k split), col = t&127.
// Each thread loads one W element per k-step and FMAs into 4 row accumulators.
__global__ __launch_bounds__(512) void k1(
    const float* __restrict__ Ha, const float* __restrict__ Hb,
    const float* __restrict__ Hc, const float* __restrict__ Wq,
    const float* __restrict__ Wk, const float* __restrict__ Wv,
    const float* __restrict__ fcw, float* __restrict__ ws) {
  __shared__ float part[4 * 4 * 128];       // [ks][lr][col]
  __shared__ float rowsL[4][128];
  const int t    = threadIdx.x;
  const int ks   = t >> 7;
  const int col  = t & 127;
  const int row0 = blockIdx.x * 4;          // 0..572, never straddles regions

  const float* X; const float* W; float* Y; int r;
  if (row0 < 64)       { X = Ha; W = Wq; Y = ws + OFF_Q;  r = row0; }
  else if (row0 < 192) { X = Hb; W = Wk; Y = ws + OFF_KB; r = row0 - 64; }
  else if (row0 < 320) { X = Hc; W = Wk; Y = ws + OFF_KC; r = row0 - 192; }
  else if (row0 < 448) { X = Hb; W = Wv; Y = ws + OFF_VB; r = row0 - 320; }
  else                 { X = Hc; W = Wv; Y = ws + OFF_VC; r = row0 - 448; }

  const float* xp = X + r * D_IN;           // 4 consecutive rows
  const int i0 = ks * 64;
  float a0 = 0.0f, a1 = 0.0f, a2 = 0.0f, a3 = 0.0f;
  #pragma unroll 8
  for (int i = 0; i < 64; ++i) {
    const float w = W[(i0 + i) * DMODEL + col];   // loaded ONCE per 4 rows
    a0 = fmaf(xp[i0 + i],             w, a0);     // x reads are wave-uniform
    a1 = fmaf(xp[D_IN + i0 + i],      w, a1);
    a2 = fmaf(xp[2 * D_IN + i0 + i],  w, a2);
    a3 = fmaf(xp[3 * D_IN + i0 + i],  w, a3);
  }
  part[(ks * 4 + 0) * 128 + col] = a0;
  part[(ks * 4 + 1) * 128 + col] = a1;
  part[(ks * 4 + 2) * 128 + col] = a2;
  part[(ks * 4 + 3) * 128 + col] = a3;
  __syncthreads();

  // reduce over ks: each of the 512 threads owns one (lr, col)
  {
    const int lr = t >> 7;                  // 0..3
    float f = part[(0 * 4 + lr) * 128 + col];
    f += part[(1 * 4 + lr) * 128 + col];
    f += part[(2 * 4 + lr) * 128 + col];
    f += part[(3 * 4 + lr) * 128 + col];
    Y[(r + lr) * DMODEL + col] = f;
    rowsL[lr][col] = f;
  }
  __syncthreads();

  if (row0 >= 320 && row0 < 448) {
    // Vb rows: pb[b][h][kk], 4 rows x 16 (h,kk)
    if (t < 64) {
      const int lr = t >> 4, e = t & 15, hh = e >> 2, kk = e & 3;
      const int b = row0 - 320 + lr;
      float s = 0.0f;
      #pragma unroll
      for (int d = 0; d < D_H; ++d)
        s = fmaf(rowsL[lr][hh * D_H + d], fcw[kk * D_H + d], s);
      ws[OFF_PB + (b * 4 + hh) * 4 + kk] = s;
    }
  } else if (row0 >= 448) {
    // Vc rows: pcx[h][cc] with kk = cc&3, 4 rows x 4 h
    if (t < 16) {
      const int lr = t >> 2, hh = t & 3;
      const int cc = row0 - 448 + lr;
      const int kk = cc & 3;
      float s = 0.0f;
      #pragma unroll
      for (int d = 0; d < D_H; ++d)
        s = fmaf(rowsL[lr][hh * D_H + d], fcw[kk * D_H + d], s);
      ws[OFF_PC + hh * N_C + cc] = s;
    }
  }
}

// ============ K2: per-(a,h) block, 1024 threads (R10 verbatim) ==============
__global__ __launch_bounds__(1024) void k2(
    const float* __restrict__ ws, const float* __restrict__ fcb,
    float* __restrict__ out) {
  __shared__ float KbL[128 * 32];           // kswz [b][d]
  __shared__ float KcL[128 * 32];           // kswz [c][d]
  __shared__ float EbcL[128 * 128];         // ebx-swizzled [b][c]
  __shared__ float qaL[32];
  __shared__ float EabL[128], EacL[128], UL[128];
  __shared__ float pbL[128 * 4];
  __shared__ float pcxL[128];
  __shared__ float red[4];

  const int t = threadIdx.x;                // 0..1023
  const int a = blockIdx.x >> 2;
  const int h = blockIdx.x & 3;

  // --- stage: Kb/Kc h-slices (4 rows/thread-group), qa, pb, pcx ---
  {
    const int d = t & 31, r0 = t >> 5;      // r0 in [0,32)
    #pragma unroll
    for (int p = 0; p < 4; ++p) {
      const int r = r0 + p * 32;
      KbL[kswz(r, d)] = ws[OFF_KB + r * DMODEL + h * D_H + d];
      KcL[kswz(r, d)] = ws[OFF_KC + r * DMODEL + h * D_H + d];
    }
    if (t < 32) qaL[t] = ws[OFF_Q + a * DMODEL + h * D_H + t];
    if (t < 512) pbL[t] = ws[OFF_PB + (t >> 2) * 16 + h * 4 + (t & 3)];
    if (t < 128) pcxL[t] = ws[OFF_PC + h * N_C + t];
  }
  __syncthreads();

  // --- Eab[b], Eac[c]: 4 threads per row, t<512 ---
  if (t < 512) {
    const int r = t >> 2, p = t & 3, d0 = p * 8;
    const float4 q0 = *(const float4*)&qaL[d0];
    const float4 q1 = *(const float4*)&qaL[d0 + 4];
    float4 x0 = *(const float4*)&KbL[kswz(r, d0)];
    float4 x1 = *(const float4*)&KbL[kswz(r, d0 + 4)];
    float s = dot4(q0, x0) + dot4(q1, x1);
    s += __shfl_xor(s, 1); s += __shfl_xor(s, 2);
    if (p == 0) EabL[r] = __expf(s * SCALE);
    x0 = *(const float4*)&KcL[kswz(r, d0)];
    x1 = *(const float4*)&KcL[kswz(r, d0 + 4)];
    s = dot4(q0, x0) + dot4(q1, x1);
    s += __shfl_xor(s, 1); s += __shfl_xor(s, 2);
    if (p == 0) EacL[r] = __expf(s * SCALE);
  }

  // --- Ebc plane: 4x4 tiles on all 1024 threads ---
  {
    const int w    = t >> 6;                // 0..15
    const int lane = t & 63;
    const int bt = (lane & 7) | ((w & 3) << 3);         // 0..31
    const int ct = ((lane >> 3) & 7) | ((w >> 2) << 3); // 0..31
    const int b0 = bt * 4, c0 = ct * 4;
    float acc[4][4];
    #pragma unroll
    for (int i = 0; i < 4; ++i)
      #pragma unroll
      for (int j = 0; j < 4; ++j) acc[i][j] = 0.0f;

    #pragma unroll
    for (int d0 = 0; d0 < 32; d0 += 4) {
      float4 cv[4];
      #pragma unroll
      for (int j = 0; j < 4; ++j) cv[j] = *(const float4*)&KcL[kswz(c0 + j, d0)];
      #pragma unroll
      for (int i = 0; i < 4; ++i) {
        const float4 bv = *(const float4*)&KbL[kswz(b0 + i, d0)];
        #pragma unroll
        for (int j = 0; j < 4; ++j) acc[i][j] += dot4(bv, cv[j]);
      }
    }
    #pragma unroll
    for (int i = 0; i < 4; ++i) {
      float4 e;
      e.x = __expf(acc[i][0] * SCALE); e.y = __expf(acc[i][1] * SCALE);
      e.z = __expf(acc[i][2] * SCALE); e.w = __expf(acc[i][3] * SCALE);
      *(float4*)&EbcL[ebx(b0 + i, c0)] = e;
    }
  }
  __syncthreads();

  // --- U[b] = sum_c Ebc[b][c]*Eac[c]: one thread per b ---
  if (t < 128) {
    float s = 0.0f;
    #pragma unroll 8
    for (int k = 0; k < 32; ++k) {
      const float4 e = *(const float4*)&EbcL[ebx(t, 4 * k)];
      const float4 v = *(const float4*)&EacL[4 * k];
      s += dot4(e, v);
    }
    UL[t] = s;
  }
  __syncthreads();

  // --- Z = sum_b Eab[b]*U[b] ---
  if (t < 128) {
    float v = EabL[t] * UL[t];
    #pragma unroll
    for (int o = 32; o > 0; o >>= 1) v += __shfl_down(v, o, 64);
    if ((t & 63) == 0) red[t >> 6] = v;
  }
  __syncthreads();
  if (t == 0) red[2] = 1.0f / (red[0] + red[1]);
  __syncthreads();
  const float zi = red[2];
  const float fb = fcb[0];

  // --- output: 1024 quads, exactly one per thread ---
  {
    const int b_loc = t >> 5;               // 0..31
    const int c0v   = (t & 31) * 4;         // 0..124
    const int b     = h * 32 + b_loc;
    const int bb    = (b_loc << 2) | (c0v >> 5);
    const int base0 = (c0v & 31) << 2;

    const float eabz = EabL[bb] * zi;
    const float4 pb4 = *(const float4*)&pbL[bb * 4];

    float rr[4];
    #pragma unroll
    for (int j = 0; j < 4; ++j) {
      const int bs = base0 + 4 * j;
      const float4 e4 = *(const float4*)&EbcL[ebx(bb, bs)];
      const float4 a4 = *(const float4*)&EacL[bs];
      const float4 x4 = *(const float4*)&pcxL[bs];
      float av = a4.x * (e4.x * (pb4.x + x4.x));
      av = fmaf(a4.y, e4.y * (pb4.y + x4.y), av);
      av = fmaf(a4.z, e4.z * (pb4.z + x4.z), av);
      av = fmaf(a4.w, e4.w * (pb4.w + x4.w), av);
      const float xj = fmaf(av, eabz, fb);
      rr[j] = 1.0f / (1.0f + __expf(-xj));
    }
    float4 res; res.x = rr[0]; res.y = rr[1]; res.z = rr[2]; res.w = rr[3];
    *(float4*)(out + a * (N_B * N_C) + b * N_C + c0v) = res;
  }
}

extern "C" void kernel_launch(void* const* d_in, const int* in_sizes, int n_in,
                              void* d_out, int out_size, void* d_ws, size_t ws_size,
                              hipStream_t stream) {
  const float* Ha  = (const float*)d_in[0];
  const float* Hb  = (const float*)d_in[1];
  const float* Hc  = (const float*)d_in[2];
  const float* Wq  = (const float*)d_in[3];
  const float* Wk  = (const float*)d_in[4];
  const float* Wv  = (const float*)d_in[5];
  const float* fcw = (const float*)d_in[6];
  const float* fcb = (const float*)d_in[7];
  float* out = (float*)d_out;
  float* ws  = (float*)d_ws;

  k1<<<144, 512, 0, stream>>>(Ha, Hb, Hc, Wq, Wk, Wv, fcw, ws);
  k2<<<256, 1024, 0, stream>>>(ws, fcb, out);
}

// Round 12
// 22.315 us; speedup vs baseline: 1.0533x; 1.0533x over previous
//
#include <hip/hip_runtime.h>
#include <math.h>

#define N_A 64
#define N_B 128
#define N_C 128
#define D_IN 256
#define D_H 32
#define NHEADS 4
#define DMODEL (D_H * NHEADS)   // 128

// Workspace layout (float offsets)
#define OFF_Q    0
#define OFF_KB   (OFF_Q   + N_A*DMODEL)
#define OFF_KC   (OFF_KB  + N_B*DMODEL)
#define OFF_VB   (OFF_KC  + N_C*DMODEL)
#define OFF_VC   (OFF_VB  + N_B*DMODEL)
#define OFF_PB   (OFF_VC  + N_C*DMODEL)      // [b][h][kk]  2048
#define OFF_PC   (OFF_PB  + N_B*NHEADS*4)    // diag PCX [h][cc] 512

#define SCALE 0.17677669529663687f  // 1/sqrt(32)

__device__ __forceinline__ float dot4(float4 a, float4 b) {
  return fmaf(a.x, b.x, fmaf(a.y, b.y, fmaf(a.z, b.z, a.w * b.w)));
}

// K-tile swizzle ([128][32] floats): spreads row-groups across 16B slots.
__device__ __forceinline__ int kswz(int row, int d) {
  return (row * 32 + d) ^ (((row >> 3) & 7) << 2);
}

// Ebc swizzle ([128][128] floats): row-dependent window for conflict-free
// GEMM stores, U-pass reads and output reads.
__device__ __forceinline__ int ebx(int b, int c) {
  return b * 128 + (c ^ (((b ^ (b >> 3)) & 7) << 2));
}

// ============ K1: projections (2 rows/block) + pb + pcx tail ================
__global__ __launch_bounds__(512) void k1(
    const float* __restrict__ Ha, const float* __restrict__ Hb,
    const float* __restrict__ Hc, const float* __restrict__ Wq,
    const float* __restrict__ Wk, const float* __restrict__ Wv,
    const float* __restrict__ fcw, float* __restrict__ ws) {
  __shared__ float part[4][2][128];
  __shared__ float rowsL[2][128];
  const int t   = threadIdx.x;
  const int r2  = blockIdx.x;               // 0..287
  const int ks  = t >> 7;
  const int col = t & 127;

  const float* X; const float* W; float* Y; int r;
  {
    const int row = r2 * 2;
    if (row < 64)       { X = Ha; W = Wq; Y = ws + OFF_Q;  r = row; }
    else if (row < 192) { X = Hb; W = Wk; Y = ws + OFF_KB; r = row - 64; }
    else if (row < 320) { X = Hc; W = Wk; Y = ws + OFF_KC; r = row - 192; }
    else if (row < 448) { X = Hb; W = Wv; Y = ws + OFF_VB; r = row - 320; }
    else                { X = Hc; W = Wv; Y = ws + OFF_VC; r = row - 448; }
  }
  const float* x0 = X + r * D_IN;
  const float* x1 = x0 + D_IN;
  const int i0 = ks * 64;
  float acc0 = 0.0f, acc1 = 0.0f;
  #pragma unroll 8
  for (int i = 0; i < 64; ++i) {
    const float w = W[(i0 + i) * DMODEL + col];
    acc0 = fmaf(x0[i0 + i], w, acc0);
    acc1 = fmaf(x1[i0 + i], w, acc1);
  }
  part[ks][0][col] = acc0;
  part[ks][1][col] = acc1;
  __syncthreads();
  if (ks == 0) {
    float f0 = 0.0f, f1 = 0.0f;
    #pragma unroll
    for (int k = 0; k < 4; ++k) { f0 += part[k][0][col]; f1 += part[k][1][col]; }
    Y[r * DMODEL + col]       = f0;
    Y[(r + 1) * DMODEL + col] = f1;
    rowsL[0][col] = f0;
    rowsL[1][col] = f1;
  }
  __syncthreads();

  const int row0 = r2 * 2;
  if (row0 >= 320 && row0 < 448) {
    if (t < 32) {                      // Vb rows: pb[b][h][kk]
      const int lr = t >> 4, e = t & 15, hh = e >> 2, kk = e & 3;
      const int b = row0 - 320 + lr;
      float s = 0.0f;
      #pragma unroll
      for (int d = 0; d < D_H; ++d)
        s = fmaf(rowsL[lr][hh * D_H + d], fcw[kk * D_H + d], s);
      ws[OFF_PB + (b * 4 + hh) * 4 + kk] = s;
    }
  } else if (row0 >= 448) {
    if (t < 8) {                       // Vc rows: pcx[h][cc], kk = cc&3
      const int lr = t >> 2, hh = t & 3;
      const int cc = row0 - 448 + lr;
      const int kk = cc & 3;
      float s = 0.0f;
      #pragma unroll
      for (int d = 0; d < D_H; ++d)
        s = fmaf(rowsL[lr][hh * D_H + d], fcw[kk * D_H + d], s);
      ws[OFF_PC + hh * N_C + cc] = s;
    }
  }
}

// ============ K2: per-(a,h) block, 1024 threads ============================
__global__ __launch_bounds__(1024) void k2(
    const float* __restrict__ ws, const float* __restrict__ fcb,
    float* __restrict__ out) {
  __shared__ float KbL[128 * 32];           // kswz [b][d]
  __shared__ float KcL[128 * 32];           // kswz [c][d]
  __shared__ float EbcL[128 * 128];         // ebx-swizzled [b][c]
  __shared__ float qaL[32];
  __shared__ float EabL[128], EacL[128], UL[128];
  __shared__ float pbL[128 * 4];
  __shared__ float pcxL[128];
  __shared__ float red[4];

  const int t = threadIdx.x;                // 0..1023
  const int a = blockIdx.x >> 2;
  const int h = blockIdx.x & 3;

  // --- stage: Kb/Kc h-slices (4 rows/thread-group), qa, pb, pcx ---
  {
    const int d = t & 31, r0 = t >> 5;      // r0 in [0,32)
    #pragma unroll
    for (int p = 0; p < 4; ++p) {
      const int r = r0 + p * 32;
      KbL[kswz(r, d)] = ws[OFF_KB + r * DMODEL + h * D_H + d];
      KcL[kswz(r, d)] = ws[OFF_KC + r * DMODEL + h * D_H + d];
    }
    if (t < 32) qaL[t] = ws[OFF_Q + a * DMODEL + h * D_H + t];
    if (t < 512) pbL[t] = ws[OFF_PB + (t >> 2) * 16 + h * 4 + (t & 3)];
    if (t < 128) pcxL[t] = ws[OFF_PC + h * N_C + t];
  }
  __syncthreads();

  // --- Eab[b], Eac[c]: 4 threads per row, t<512 ---
  if (t < 512) {
    const int r = t >> 2, p = t & 3, d0 = p * 8;
    const float4 q0 = *(const float4*)&qaL[d0];
    const float4 q1 = *(const float4*)&qaL[d0 + 4];
    float4 x0 = *(const float4*)&KbL[kswz(r, d0)];
    float4 x1 = *(const float4*)&KbL[kswz(r, d0 + 4)];
    float s = dot4(q0, x0) + dot4(q1, x1);
    s += __shfl_xor(s, 1); s += __shfl_xor(s, 2);
    if (p == 0) EabL[r] = __expf(s * SCALE);
    x0 = *(const float4*)&KcL[kswz(r, d0)];
    x1 = *(const float4*)&KcL[kswz(r, d0 + 4)];
    s = dot4(q0, x0) + dot4(q1, x1);
    s += __shfl_xor(s, 1); s += __shfl_xor(s, 2);
    if (p == 0) EacL[r] = __expf(s * SCALE);
  }

  // --- Ebc plane: 4x4 tiles on all 1024 threads ---
  // wave spans 8 b-tiles x 8 c-tiles -> conflict-free KbL/KcL reads & stores.
  {
    const int w    = t >> 6;                // 0..15
    const int lane = t & 63;
    const int bt = (lane & 7) | ((w & 3) << 3);        // 0..31
    const int ct = ((lane >> 3) & 7) | ((w >> 2) << 3); // 0..31
    const int b0 = bt * 4, c0 = ct * 4;
    float acc[4][4];
    #pragma unroll
    for (int i = 0; i < 4; ++i)
      #pragma unroll
      for (int j = 0; j < 4; ++j) acc[i][j] = 0.0f;

    #pragma unroll
    for (int d0 = 0; d0 < 32; d0 += 4) {
      float4 cv[4];
      #pragma unroll
      for (int j = 0; j < 4; ++j) cv[j] = *(const float4*)&KcL[kswz(c0 + j, d0)];
      #pragma unroll
      for (int i = 0; i < 4; ++i) {
        const float4 bv = *(const float4*)&KbL[kswz(b0 + i, d0)];
        #pragma unroll
        for (int j = 0; j < 4; ++j) acc[i][j] += dot4(bv, cv[j]);
      }
    }
    #pragma unroll
    for (int i = 0; i < 4; ++i) {
      float4 e;
      e.x = __expf(acc[i][0] * SCALE); e.y = __expf(acc[i][1] * SCALE);
      e.z = __expf(acc[i][2] * SCALE); e.w = __expf(acc[i][3] * SCALE);
      *(float4*)&EbcL[ebx(b0 + i, c0)] = e;
    }
  }
  __syncthreads();

  // --- U[b] = sum_c Ebc[b][c]*Eac[c]: one thread per b ---
  if (t < 128) {
    float s = 0.0f;
    #pragma unroll 8
    for (int k = 0; k < 32; ++k) {
      const float4 e = *(const float4*)&EbcL[ebx(t, 4 * k)];
      const float4 v = *(const float4*)&EacL[4 * k];
      s += dot4(e, v);
    }
    UL[t] = s;
  }
  __syncthreads();

  // --- Z = sum_b Eab[b]*U[b] ---
  if (t < 128) {
    float v = EabL[t] * UL[t];
    #pragma unroll
    for (int o = 32; o > 0; o >>= 1) v += __shfl_down(v, o, 64);
    if ((t & 63) == 0) red[t >> 6] = v;
  }
  __syncthreads();
  if (t == 0) red[2] = 1.0f / (red[0] + red[1]);
  __syncthreads();
  const float zi = red[2];
  const float fb = fcb[0];

  // --- output: 1024 quads, exactly one per thread ---
  {
    const int b_loc = t >> 5;               // 0..31
    const int c0v   = (t & 31) * 4;         // 0..124
    const int b     = h * 32 + b_loc;
    const int bb    = (b_loc << 2) | (c0v >> 5);
    const int base0 = (c0v & 31) << 2;

    const float eabz = EabL[bb] * zi;
    const float4 pb4 = *(const float4*)&pbL[bb * 4];

    float rr[4];
    #pragma unroll
    for (int j = 0; j < 4; ++j) {
      const int bs = base0 + 4 * j;
      const float4 e4 = *(const float4*)&EbcL[ebx(bb, bs)];
      const float4 a4 = *(const float4*)&EacL[bs];
      const float4 x4 = *(const float4*)&pcxL[bs];
      float av = a4.x * (e4.x * (pb4.x + x4.x));
      av = fmaf(a4.y, e4.y * (pb4.y + x4.y), av);
      av = fmaf(a4.z, e4.z * (pb4.z + x4.z), av);
      av = fmaf(a4.w, e4.w * (pb4.w + x4.w), av);
      const float xj = fmaf(av, eabz, fb);
      rr[j] = 1.0f / (1.0f + __expf(-xj));
    }
    float4 res; res.x = rr[0]; res.y = rr[1]; res.z = rr[2]; res.w = rr[3];
    *(float4*)(out + a * (N_B * N_C) + b * N_C + c0v) = res;
  }
}

extern "C" void kernel_launch(void* const* d_in, const int* in_sizes, int n_in,
                              void* d_out, int out_size, void* d_ws, size_t ws_size,
                              hipStream_t stream) {
  const float* Ha  = (const float*)d_in[0];
  const float* Hb  = (const float*)d_in[1];
  const float* Hc  = (const float*)d_in[2];
  const float* Wq  = (const float*)d_in[3];
  const float* Wk  = (const float*)d_in[4];
  const float* Wv  = (const float*)d_in[5];
  const float* fcw = (const float*)d_in[6];
  const float* fcb = (const float*)d_in[7];
  float* out = (float*)d_out;
  float* ws  = (float*)d_ws;

  k1<<<288, 512, 0, stream>>>(Ha, Hb, Hc, Wq, Wk, Wv, fcw, ws);
  k2<<<256, 1024, 0, stream>>>(ws, fcb, out);
}